// Round 1
// baseline (3291.167 us; speedup 1.0000x reference)
//
#include <hip/hip_runtime.h>
#include <math.h>

// SLAYER 2-layer SNN, fused per-layer kernel: GEMM (fp64 acc) + 62-tap causal
// PSP conv (fp64) + sequential threshold/refractory scan (fp64, LDS state).
// Precision strategy: fp64 end-to-end; SRM/REF taps computed in double then
// rounded to fp32 (matching the reference's np.float32 kernels) and widened.

#define TT     256   // timesteps
#define KLEN   62    // alpha-kernel length (t=0..61; v(62)=0.00907 < 0.01 -> break)
#define OTILE  8     // output neurons per block
#define BLOCK  256   // threads per block (thread == timestep)

template <typename XT, typename ST>
__global__ __launch_bounds__(BLOCK)
void snn_layer(const XT* __restrict__ x,      // [B][I][TT]  (float or u8 spikes)
               const float* __restrict__ w,   // [O][I]
               ST* __restrict__ s_out,        // [B][O][TT]  (u8 or float spikes)
               int I, int O)
{
    __shared__ double w_sh[64][OTILE];        // 4 KB   staged weight chunk (as f64)
    __shared__ double a_sh[OTILE][TT];        // 16 KB  pre-PSP activations
    __shared__ double u_sh[OTILE][TT];        // 16 KB  PSP membrane input
    __shared__ double r_sh[OTILE][TT + 64];   // 20 KB  pending refractory (padded tail)
    __shared__ float  srm_sh[KLEN];
    __shared__ float  ref_sh[KLEN];

    const int tid = threadIdx.x;              // == timestep t for GEMM/conv phases
    const int b   = blockIdx.y;
    const int o0  = blockIdx.x * OTILE;

    // Alpha kernels, computed in double exactly like the Python loop, then fp32-cast.
    if (tid < KLEN) {
        double v = (double)tid / 8.0 * exp(1.0 - (double)tid / 8.0);
        srm_sh[tid] = (float)v;                 // mult = 1
        ref_sh[tid] = (float)(-20.0 * v);       // mult = -scaleRef*theta = -20
    }
    for (int e = tid; e < OTILE * (TT + 64); e += BLOCK)
        (&r_sh[0][0])[e] = 0.0;

    // ---------------- GEMM: acc[o] = sum_i w[o0+o][i] * x[b][i][tid] ----------
    double acc[OTILE];
#pragma unroll
    for (int o = 0; o < OTILE; ++o) acc[o] = 0.0;

    const XT* xp = x + (size_t)b * I * TT + tid;

    for (int i0 = 0; i0 < I; i0 += 64) {
        __syncthreads();   // protect previous chunk reads (and initial zeroing)
        for (int e = tid; e < 64 * OTILE; e += BLOCK) {
            int il = e & 63, o = e >> 6;       // coalesced global reads along i
            w_sh[il][o] = (double)w[(size_t)(o0 + o) * I + (i0 + il)];
        }
        __syncthreads();
#pragma unroll 4
        for (int il = 0; il < 64; ++il) {
            double xv = (double)xp[(size_t)(i0 + il) * TT];
#pragma unroll
            for (int o = 0; o < OTILE; ++o)
                acc[o] = fma(xv, w_sh[il][o], acc[o]);   // broadcast LDS reads
        }
    }

#pragma unroll
    for (int o = 0; o < OTILE; ++o) a_sh[o][tid] = acc[o];
    __syncthreads();

    // ---------------- causal PSP conv: u[t] = sum_{k=1..61} srm[k]*a[t-k] -----
    // (srm[0] == 0 exactly, so k starts at 1)
#pragma unroll
    for (int o = 0; o < OTILE; ++o) acc[o] = 0.0;
    const int kmax = (tid < KLEN - 1) ? tid : (KLEN - 1);
    for (int k = 1; k <= kmax; ++k) {
        double sv = (double)srm_sh[k];
#pragma unroll
        for (int o = 0; o < OTILE; ++o)
            acc[o] = fma(sv, a_sh[o][tid - k], acc[o]);
    }
#pragma unroll
    for (int o = 0; o < OTILE; ++o) u_sh[o][tid] = acc[o];
    __syncthreads();

    // ---------------- sequential spike/refractory scan ------------------------
    // Wave wv owns neurons oA=2*wv, oB=2*wv+1 (interleaved for latency hiding).
    // All 64 lanes read the same u/r -> spike decision is wave-uniform.
    // On a spike at t, lane l (1..61) adds REF[l] to r[t+l] (the ref_tail).
    float* s_lds = (float*)&a_sh[0][0];        // a_sh is dead after conv; reuse
    const int wv = tid >> 6, lane = tid & 63;
    const bool updl = (lane >= 1 && lane < KLEN);
    const double refv = updl ? (double)ref_sh[lane] : 0.0;
    const int oA = wv * 2, oB = oA + 1;
    for (int t = 0; t < TT; ++t) {
        double uA = u_sh[oA][t] + r_sh[oA][t];
        double uB = u_sh[oB][t] + r_sh[oB][t];
        const bool sA = (uA >= 10.0);
        const bool sB = (uB >= 10.0);
        if (lane == 0) {
            s_lds[oA * TT + t] = sA ? 1.0f : 0.0f;
            s_lds[oB * TT + t] = sB ? 1.0f : 0.0f;
        }
        if (sA & updl) r_sh[oA][t + lane] += refv;   // t+lane <= 316 < 320 (padded)
        if (sB & updl) r_sh[oB][t + lane] += refv;
    }
    __syncthreads();

    // ---------------- write spikes -------------------------------------------
    ST* op = s_out + ((size_t)b * O + o0) * TT;
    for (int e = tid; e < OTILE * TT; e += BLOCK)
        op[e] = (ST)s_lds[e];
}

extern "C" void kernel_launch(void* const* d_in, const int* in_sizes, int n_in,
                              void* d_out, int out_size, void* d_ws, size_t ws_size,
                              hipStream_t stream)
{
    const float* x  = (const float*)d_in[0];   // [32][1024][256] input spikes
    const float* w1 = (const float*)d_in[1];   // [2048][1024]
    const float* w2 = (const float*)d_in[2];   // [512][2048]
    unsigned char* s1 = (unsigned char*)d_ws;  // [32][2048][256] hidden spikes, 16.8 MB
    float* out = (float*)d_out;                // [32][512][256]

    // Layer 1: 1024 -> 2048
    snn_layer<float, unsigned char>
        <<<dim3(2048 / OTILE, 32), dim3(BLOCK), 0, stream>>>(x, w1, s1, 1024, 2048);
    // Layer 2: 2048 -> 512
    snn_layer<unsigned char, float>
        <<<dim3(512 / OTILE, 32), dim3(BLOCK), 0, stream>>>(s1, w2, out, 2048, 512);
}

// Round 2
// 2072.835 us; speedup vs baseline: 1.5878x; 1.5878x over previous
//
#include <hip/hip_runtime.h>
#include <math.h>
#include <stdint.h>

// SLAYER 2-layer SNN, sparse-event redesign.
// Pipeline: bitify(x) -> layer1(bits->bits) -> layer2(bits->bits) -> bits_to_f32.
// Layer kernel: per block = 64 output neurons (lane=o) x one batch, t chunked by 16.
//   GEMM: wave-uniform spike-word bit loop; per spiking input i, one LDS read of
//         w[i][lane] (f32->f64) + v_add_f64  => 64 MACs per event, fp64 exact.
//   PSP conv: 61 fp64 taps (fp32-rounded, matching reference) over an LDS a-ring.
//   Scan: lane-per-neuron; refractory r = sum ref[age] over a 61-bit spike mask.
// All accumulation fp64 (round-1 matched reference with absmax 0.0).

#define TT     256
#define KLEN   62          // alpha kernel taps 0..61 (v(62) < 1% of peak -> truncated)
#define THETA  10.0
#define CHUNK  16          // timesteps per pipeline chunk
#define NCHUNK (TT/CHUNK)  // 16
#define RING   80          // 5 chunk slots >= 61 history + CHUNK
#define RPAD   65          // padded row length (in doubles / floats per layout)

// ---------------------------------------------------------------- bitify ----
__global__ __launch_bounds__(256)
void bitify(const float* __restrict__ x, uint32_t* __restrict__ bits)
{
    // x: [32][1024][256] f32 {0,1};  bits: [b][t][32 words], word wi bit j = x[b][wi*32+j][t]
    const int b  = blockIdx.x;
    const int ig = blockIdx.y;            // i-group of 128 inputs (4 words)
    const int t  = threadIdx.x;           // 0..255
    const float*  xp = x    + ((size_t)b*1024 + ig*128)*TT + t;
    uint32_t*     bp = bits + ((size_t)b*TT + t)*32 + ig*4;
    for (int wi = 0; wi < 4; ++wi) {
        uint32_t wb = 0;
        #pragma unroll
        for (int j = 0; j < 32; ++j)
            wb |= (xp[(size_t)(wi*32 + j)*TT] >= 0.5f) ? (1u << j) : 0u;
        bp[wi] = wb;
    }
}

// ------------------------------------------------------------ layer kernel --
template<int I>
__global__ __launch_bounds__(256)
void snn_layer_sparse(const uint32_t* __restrict__ bits_in,   // [B][TT][I/32]
                      const float*    __restrict__ w,         // [O][I]
                      uint32_t*       __restrict__ bits_out,  // [B][TT][O/32]
                      int O)
{
    __shared__ double ring[RING][RPAD];   // 41.6 KB  a-values, row = t mod RING
    __shared__ double wu[2080];           // 16.6 KB  union: wsh f32[64][RPAD] / ush f64[CHUNK][RPAD]
    __shared__ double srm64[KLEN];
    __shared__ double ref64[KLEN];

    float*  wsh = (float*)wu;
    double* ush = wu;

    const int tid  = threadIdx.x;
    const int lane = tid & 63;
    const int wvu  = __builtin_amdgcn_readfirstlane(tid >> 6);   // wave id 0..3
    const int b    = blockIdx.y;
    const int o0   = blockIdx.x * 64;
    const int IW   = I / 32;

    // fp32-rounded taps (identical to reference's np.float32 kernels), widened to f64
    if (tid < KLEN) {
        double v = (double)tid / 8.0 * exp(1.0 - (double)tid / 8.0);
        srm64[tid] = (double)(float)v;
        ref64[tid] = (double)(float)(-20.0 * v);
    }
    for (int e = tid; e < RING*RPAD; e += 256) ((double*)ring)[e] = 0.0;
    // (no explicit sync needed: gemm's first internal barrier precedes any ring write)

    // ---- GEMM one chunk: a[t][o] = sum over spiking i of w[o][i] (fp64) ----
    auto gemm_chunk = [&](int c) {
        const int t0 = c * CHUNK;
        double acc[CHUNK/4];
        #pragma unroll
        for (int j = 0; j < CHUNK/4; ++j) acc[j] = 0.0;

        for (int ic = 0; ic < I/64; ++ic) {
            __syncthreads();   // protect previous wsh/ush readers
            {   // stage w[o0..o0+64][ic*64..+64] -> wsh[il][o]  (coalesced float4 reads)
                const int obase = tid >> 4;          // 0..15
                const int il4   = (tid & 15) * 4;
                #pragma unroll
                for (int p4 = 0; p4 < 4; ++p4) {
                    const int oo = obase + p4*16;
                    const float4 wv4 = *(const float4*)(w + (size_t)(o0+oo)*I + ic*64 + il4);
                    wsh[(il4+0)*RPAD + oo] = wv4.x;
                    wsh[(il4+1)*RPAD + oo] = wv4.y;
                    wsh[(il4+2)*RPAD + oo] = wv4.z;
                    wsh[(il4+3)*RPAD + oo] = wv4.w;
                }
            }
            __syncthreads();
            #pragma unroll
            for (int j = 0; j < CHUNK/4; ++j) {
                const int t = t0 + wvu*(CHUNK/4) + j;
                const uint64_t raw =
                    *(const uint64_t*)(bits_in + ((size_t)b*TT + t)*IW + ic*2);
                // force the spike word into SGPRs -> scalar bit loop, uniform branches
                const uint32_t mlo = __builtin_amdgcn_readfirstlane((uint32_t)raw);
                const uint32_t mhi = __builtin_amdgcn_readfirstlane((uint32_t)(raw >> 32));
                uint64_t m = ((uint64_t)mhi << 32) | mlo;
                double a0 = 0.0, a1 = 0.0, a2 = 0.0, a3 = 0.0;
                while (m) {   // 4-wide: keep several LDS reads in flight
                    float f0 = 0.f, f1 = 0.f, f2 = 0.f, f3 = 0.f;
                    int p = __builtin_ctzll(m); m &= m - 1;
                    f0 = wsh[p*RPAD + lane];
                    if (m) { p = __builtin_ctzll(m); m &= m - 1; f1 = wsh[p*RPAD + lane]; }
                    if (m) { p = __builtin_ctzll(m); m &= m - 1; f2 = wsh[p*RPAD + lane]; }
                    if (m) { p = __builtin_ctzll(m); m &= m - 1; f3 = wsh[p*RPAD + lane]; }
                    a0 += (double)f0; a1 += (double)f1; a2 += (double)f2; a3 += (double)f3;
                }
                acc[j] += (a0 + a1) + (a2 + a3);
            }
        }
        #pragma unroll
        for (int j = 0; j < CHUNK/4; ++j) {
            const int t = t0 + wvu*(CHUNK/4) + j;
            ring[t % RING][lane] = acc[j];           // consecutive lanes -> conflict-free
        }
    };

    // ---- causal PSP conv for one chunk: u[t] = sum_{k=1..61} srm[k]*a[t-k] ----
    auto conv_chunk = [&](int c) {
        const int t0 = c * CHUNK;
        const int tl = tid & (CHUNK-1);   // 0..15
        const int os = tid >> 4;          // 0..15 -> o = os*4 .. +4
        const int t  = t0 + tl;
        double u0 = 0, u1 = 0, u2 = 0, u3 = 0;
        for (int k = 1; k < KLEN; ++k) {
            const double sv  = srm64[k];
            const int    row = (t - k + RING) % RING;   // t-k >= -61 -> +80 >= 19
            const double* ap = &ring[row][os*4];
            u0 = fma(sv, ap[0], u0);
            u1 = fma(sv, ap[1], u1);
            u2 = fma(sv, ap[2], u2);
            u3 = fma(sv, ap[3], u3);
        }
        double* up = &ush[tl*RPAD + os*4];
        up[0] = u0; up[1] = u1; up[2] = u2; up[3] = u3;
    };

    // ---- sequential spike/refractory scan (wave0, lane = neuron) ----
    uint64_t mask = 0;   // bit p = own spike at age p+1 (ages 1..61 kept)
    auto scan_chunk = [&](int c) {
        const int t0 = c * CHUNK;
        for (int tl = 0; tl < CHUNK; ++tl) {
            const double u = ush[tl*RPAD + lane];
            uint64_t m = mask;
            double r0 = 0.0, r1 = 0.0;
            while (m) {
                int p = __builtin_ctzll(m); m &= m - 1;
                r0 += ref64[p + 1];
                if (m) { int q = __builtin_ctzll(m); m &= m - 1; r1 += ref64[q + 1]; }
            }
            const bool s = (u + (r0 + r1)) >= THETA;
            const uint64_t bal = __ballot(s);        // bit l = lane l = neuron o0+l
            if (lane == 0)
                *(uint64_t*)(bits_out + ((size_t)b*TT + (t0 + tl))*(O/32) + (o0 >> 5)) = bal;
            mask = ((mask << 1) | (s ? 1ull : 0ull)) & ((1ull << 61) - 1ull);
        }
    };

    // ---- pipeline: conv(c) -> scan(c) -> gemm(c+1), ring slots make this safe ----
    gemm_chunk(0);
    for (int c = 0; c < NCHUNK; ++c) {
        __syncthreads();                 // ring(c) visible
        conv_chunk(c);
        __syncthreads();                 // ush visible to wave0
        if (wvu == 0) scan_chunk(c);
        __syncthreads();                 // ush free for wsh restaging
        if (c + 1 < NCHUNK) gemm_chunk(c + 1);
    }
}

// ------------------------------------------------------------- epilogue -----
__global__ __launch_bounds__(256)
void bits_to_f32(const uint32_t* __restrict__ bits, float* __restrict__ out, int O)
{
    // bits: [b][t][O/32] -> out: [b][o][t] f32 {0,1}
    const int b  = blockIdx.y;
    const int o  = blockIdx.x*4 + (threadIdx.x >> 6);
    const int tq = (threadIdx.x & 63) * 4;
    const uint32_t* bp  = bits + (size_t)b*TT*(O/32) + (o >> 5);
    const uint32_t  bit = 1u << (o & 31);
    float4 v;
    v.x = (bp[(size_t)(tq+0)*(O/32)] & bit) ? 1.0f : 0.0f;
    v.y = (bp[(size_t)(tq+1)*(O/32)] & bit) ? 1.0f : 0.0f;
    v.z = (bp[(size_t)(tq+2)*(O/32)] & bit) ? 1.0f : 0.0f;
    v.w = (bp[(size_t)(tq+3)*(O/32)] & bit) ? 1.0f : 0.0f;
    *(float4*)(out + ((size_t)b*O + o)*TT + tq) = v;
}

// ------------------------------------------------------------- launcher -----
extern "C" void kernel_launch(void* const* d_in, const int* in_sizes, int n_in,
                              void* d_out, int out_size, void* d_ws, size_t ws_size,
                              hipStream_t stream)
{
    const float* x  = (const float*)d_in[0];   // [32][1024][256]
    const float* w1 = (const float*)d_in[1];   // [2048][1024]
    const float* w2 = (const float*)d_in[2];   // [512][2048]
    float* out = (float*)d_out;                // [32][512][256]

    uint32_t* bits1 = (uint32_t*)d_ws;                       // 32*256*32 words = 1 MB
    uint32_t* bitsH = bits1 + (size_t)32*256*32;             // 32*256*64 words = 2 MB
    uint32_t* bits2 = bitsH + (size_t)32*256*64;             // 32*256*16 words = 0.5 MB

    bitify<<<dim3(32, 8), 256, 0, stream>>>(x, bits1);
    snn_layer_sparse<1024><<<dim3(2048/64, 32), 256, 0, stream>>>(bits1, w1, bitsH, 2048);
    snn_layer_sparse<2048><<<dim3(512/64, 32), 256, 0, stream>>>(bitsH, w2, bits2, 512);
    bits_to_f32<<<dim3(512/4, 32), 256, 0, stream>>>(bits2, out, 512);
}

// Round 3
// 1962.461 us; speedup vs baseline: 1.6771x; 1.0562x over previous
//
#include <hip/hip_runtime.h>
#include <math.h>
#include <stdint.h>

// SLAYER 2-layer SNN. Round 3: de-fused pipeline.
//   bitify -> per layer: [sparse bit-GEMM -> dense FIR conv -> sequential scan]
//   -> bits_to_f32.
// All accumulation fp64 with fp32-rounded alpha-kernel taps (matched reference
// with absmax 0.0 in rounds 1-2). Big f64 a/u buffers live in d_ws; the o-dim
// is sliced adaptively to fit ws_size, with a fallback to the round-2 fused
// kernel if ws is too small.

#define TT     256
#define KLEN   62          // taps 0..61
#define THETA  10.0

// ================================ bitify ====================================
__global__ __launch_bounds__(256)
void bitify(const float* __restrict__ x, uint32_t* __restrict__ bits)
{
    // x: [32][1024][256] f32 {0,1}; bits: [b][t][32 words], word wi bit j = x[b][wi*32+j][t]
    const int b  = blockIdx.x;
    const int ig = blockIdx.y;            // group of 128 inputs (4 words)
    const int t  = threadIdx.x;
    const float*  xp = x    + ((size_t)b*1024 + ig*128)*TT + t;
    uint32_t*     bp = bits + ((size_t)b*TT + t)*32 + ig*4;
    for (int wi = 0; wi < 4; ++wi) {
        uint32_t wb = 0;
        #pragma unroll
        for (int j = 0; j < 32; ++j)
            wb |= (xp[(size_t)(wi*32 + j)*TT] >= 0.5f) ? (1u << j) : 0u;
        bp[wi] = wb;
    }
}

// ========================== fast path: sparse GEMM ==========================
// a[b][t][o] = sum over spiking i of w[o][i]   (fp64, event order == round 2)
// block: 64 outputs x 128 t (4 waves x 32 t). lane = o, spike masks wave-uniform.
template<int I>
__global__ __launch_bounds__(256, 4)
void gemm_sparse(const uint32_t* __restrict__ bits_in,   // [B][TT][I/32]
                 const float*    __restrict__ w,         // slice base, stride I
                 double*         __restrict__ a_out,     // [B][TT][OS]
                 int OS)
{
    constexpr int IW = I / 32;
    __shared__ float wsh[64 * 65];

    const int tid  = threadIdx.x;
    const int lane = tid & 63;
    const int wvu  = tid >> 6;
    const int b    = blockIdx.z;
    const int o0   = blockIdx.x * 64;
    const int t0   = blockIdx.y * 128 + wvu * 32;

    double acc[32];
    #pragma unroll
    for (int j = 0; j < 32; ++j) acc[j] = 0.0;

    for (int ic = 0; ic < I / 64; ++ic) {
        __syncthreads();
        {   // stage w[o0..+64][ic*64..+64] -> wsh[il][o], padded stride 65
            const int obase = tid >> 4, il4 = (tid & 15) * 4;
            #pragma unroll
            for (int p4 = 0; p4 < 4; ++p4) {
                const int oo = obase + p4 * 16;
                const float4 wv4 = *(const float4*)(w + (size_t)(o0 + oo) * I + ic * 64 + il4);
                wsh[(il4 + 0) * 65 + oo] = wv4.x;
                wsh[(il4 + 1) * 65 + oo] = wv4.y;
                wsh[(il4 + 2) * 65 + oo] = wv4.z;
                wsh[(il4 + 3) * 65 + oo] = wv4.w;
            }
        }
        __syncthreads();
        #pragma unroll
        for (int j = 0; j < 32; ++j) {
            const uint64_t raw =
                *(const uint64_t*)(bits_in + ((size_t)b * TT + t0 + j) * IW + ic * 2);
            const uint32_t mlo = __builtin_amdgcn_readfirstlane((uint32_t)raw);
            const uint32_t mhi = __builtin_amdgcn_readfirstlane((uint32_t)(raw >> 32));
            uint64_t m = ((uint64_t)mhi << 32) | mlo;
            double a0 = 0.0, a1 = 0.0, a2 = 0.0, a3 = 0.0;
            while (m) {   // 4-wide: several LDS reads in flight
                float f0 = 0.f, f1 = 0.f, f2 = 0.f, f3 = 0.f;
                int p = __builtin_ctzll(m); m &= m - 1;
                f0 = wsh[p * 65 + lane];
                if (m) { p = __builtin_ctzll(m); m &= m - 1; f1 = wsh[p * 65 + lane]; }
                if (m) { p = __builtin_ctzll(m); m &= m - 1; f2 = wsh[p * 65 + lane]; }
                if (m) { p = __builtin_ctzll(m); m &= m - 1; f3 = wsh[p * 65 + lane]; }
                a0 += (double)f0; a1 += (double)f1; a2 += (double)f2; a3 += (double)f3;
            }
            acc[j] += (a0 + a1) + (a2 + a3);
        }
    }
    double* aout = a_out + ((size_t)b * TT + t0) * OS + o0 + lane;
    #pragma unroll
    for (int j = 0; j < 32; ++j) aout[(size_t)j * OS] = acc[j];
}

// ========================== fast path: FIR conv =============================
// u[b][t][o] = sum_{k=1..61} srm[k] * a[b][t-k][o].
// block: 64 o x 64 t tile; a staged (125 rows x 64 o) in LDS; each thread
// computes 16 t register-blocked by 4 (sliding coeff window, no re-reads).
__global__ __launch_bounds__(256)
void psp_conv(const double* __restrict__ a, double* __restrict__ u, int OS)
{
    __shared__ double ash[125 * 64];   // 62.5 KB
    __shared__ double srmE[68];        // srmE[i] = srm[i-2] for i-2 in [1,61], else 0

    const int tid = threadIdx.x;
    if (tid < 68) {
        const int k = tid - 2;
        double v = 0.0;
        if (k >= 1 && k <= 61) {
            double wv = (double)k / 8.0 * exp(1.0 - (double)k / 8.0);
            v = (double)(float)wv;     // fp32-rounded tap, widened
        }
        srmE[tid] = v;
    }
    const int b  = blockIdx.z;
    const int T0 = blockIdx.y * 64;
    const int og = blockIdx.x * 64;
    const double* ap = a + (size_t)b * TT * OS + og;
    for (int e = tid; e < 125 * 64; e += 256) {
        const int r = e >> 6, o = e & 63;
        const int t = T0 - 61 + r;
        ash[e] = (t >= 0) ? ap[(size_t)t * OS + o] : 0.0;
    }
    __syncthreads();

    const int o   = tid & 63;
    const int tb0 = (tid >> 6) * 16;
    for (int g = 0; g < 4; ++g) {
        const int tb = tb0 + g * 4;     // u for t = T0+tb .. +3
        double u0 = 0, u1 = 0, u2 = 0, u3 = 0;
        double w1 = srmE[64], w2 = srmE[65], w3 = srmE[66];   // all zero pads
        for (int d = 0; d < 64; d += 4) {
            const double av0 = ash[(tb + d + 0) * 64 + o];
            const double av1 = ash[(tb + d + 1) * 64 + o];
            const double av2 = ash[(tb + d + 2) * 64 + o];
            const double av3 = ash[(tb + d + 3) * 64 + o];
            const double n0 = srmE[63 - d], n1 = srmE[62 - d];
            const double n2 = srmE[61 - d], n3 = srmE[60 - d];
            u0 = fma(n0, av0, u0); u1 = fma(w1, av0, u1); u2 = fma(w2, av0, u2); u3 = fma(w3, av0, u3);
            u0 = fma(n1, av1, u0); u1 = fma(n0, av1, u1); u2 = fma(w1, av1, u2); u3 = fma(w2, av1, u3);
            u0 = fma(n2, av2, u0); u1 = fma(n1, av2, u1); u2 = fma(n0, av2, u2); u3 = fma(w1, av2, u3);
            u0 = fma(n3, av3, u0); u1 = fma(n2, av3, u1); u2 = fma(n1, av3, u2); u3 = fma(n0, av3, u3);
            w1 = n3; w2 = n2; w3 = n1;
        }
        double* uo = u + ((size_t)b * TT + T0 + tb) * OS + og + o;
        uo[0] = u0; uo[OS] = u1; uo[2 * (size_t)OS] = u2; uo[3 * (size_t)OS] = u3;
    }
}

// ========================== fast path: scan =================================
// lane = neuron. 256 sequential steps; refractory r = sum ref[age] over a
// 61-bit own-spike-history mask; coalesced u loads prefetched 4 ahead.
__global__ __launch_bounds__(256)
void scan_spikes(const double* __restrict__ u, uint32_t* __restrict__ bits_out,
                 int OS, int obase, int OW)
{
    __shared__ double ref64[KLEN];
    const int tid = threadIdx.x;
    if (tid < KLEN) {
        double v = (double)tid / 8.0 * exp(1.0 - (double)tid / 8.0);
        ref64[tid] = (double)(float)(-20.0 * v);
    }
    __syncthreads();

    const int b    = blockIdx.y;
    const int o    = blockIdx.x * 256 + tid;   // within slice
    const int lane = tid & 63;
    const int widx = (obase + blockIdx.x * 256 + (tid >> 6) * 64) >> 5;  // u32-word idx, even
    const double* up = u + (size_t)b * TT * OS + o;

    uint64_t mask = 0;
    double cur0 = up[0], cur1 = up[OS], cur2 = up[2 * (size_t)OS], cur3 = up[3 * (size_t)OS];
    for (int t0 = 0; t0 < TT; t0 += 4) {
        double nx0 = 0, nx1 = 0, nx2 = 0, nx3 = 0;
        if (t0 + 4 < TT) {
            const double* pp = up + (size_t)(t0 + 4) * OS;
            nx0 = pp[0]; nx1 = pp[OS]; nx2 = pp[2 * (size_t)OS]; nx3 = pp[3 * (size_t)OS];
        }
        #pragma unroll
        for (int q = 0; q < 4; ++q) {
            const double uv = (q == 0) ? cur0 : (q == 1) ? cur1 : (q == 2) ? cur2 : cur3;
            uint64_t m = mask;
            double r0 = 0.0, r1 = 0.0;
            while (m) {
                int p = __builtin_ctzll(m); m &= m - 1;
                r0 += ref64[p + 1];
                if (m) { int pq = __builtin_ctzll(m); m &= m - 1; r1 += ref64[pq + 1]; }
            }
            const bool s = (uv + (r0 + r1)) >= THETA;
            const uint64_t bal = __ballot(s);
            if (lane == 0)
                *(uint64_t*)(bits_out + ((size_t)b * TT + t0 + q) * OW + widx) = bal;
            mask = ((mask << 1) | (s ? 1ull : 0ull)) & ((1ull << 61) - 1ull);
        }
        cur0 = nx0; cur1 = nx1; cur2 = nx2; cur3 = nx3;
    }
}

// =================== fallback: round-2 fused layer kernel ===================
#define CHUNK  16
#define NCHUNK (TT/CHUNK)
#define RING   80
#define RPAD   65

template<int I>
__global__ __launch_bounds__(256)
void snn_layer_sparse(const uint32_t* __restrict__ bits_in,
                      const float*    __restrict__ w,
                      uint32_t*       __restrict__ bits_out,
                      int O)
{
    __shared__ double ring[RING][RPAD];
    __shared__ double wu[2080];
    __shared__ double srm64[KLEN];
    __shared__ double ref64[KLEN];

    float*  wsh = (float*)wu;
    double* ush = wu;

    const int tid  = threadIdx.x;
    const int lane = tid & 63;
    const int wvu  = __builtin_amdgcn_readfirstlane(tid >> 6);
    const int b    = blockIdx.y;
    const int o0   = blockIdx.x * 64;
    const int IW   = I / 32;

    if (tid < KLEN) {
        double v = (double)tid / 8.0 * exp(1.0 - (double)tid / 8.0);
        srm64[tid] = (double)(float)v;
        ref64[tid] = (double)(float)(-20.0 * v);
    }
    for (int e = tid; e < RING*RPAD; e += 256) ((double*)ring)[e] = 0.0;

    auto gemm_chunk = [&](int c) {
        const int t0 = c * CHUNK;
        double acc[CHUNK/4];
        #pragma unroll
        for (int j = 0; j < CHUNK/4; ++j) acc[j] = 0.0;
        for (int ic = 0; ic < I/64; ++ic) {
            __syncthreads();
            {
                const int obase = tid >> 4;
                const int il4   = (tid & 15) * 4;
                #pragma unroll
                for (int p4 = 0; p4 < 4; ++p4) {
                    const int oo = obase + p4*16;
                    const float4 wv4 = *(const float4*)(w + (size_t)(o0+oo)*I + ic*64 + il4);
                    wsh[(il4+0)*RPAD + oo] = wv4.x;
                    wsh[(il4+1)*RPAD + oo] = wv4.y;
                    wsh[(il4+2)*RPAD + oo] = wv4.z;
                    wsh[(il4+3)*RPAD + oo] = wv4.w;
                }
            }
            __syncthreads();
            #pragma unroll
            for (int j = 0; j < CHUNK/4; ++j) {
                const int t = t0 + wvu*(CHUNK/4) + j;
                const uint64_t raw =
                    *(const uint64_t*)(bits_in + ((size_t)b*TT + t)*IW + ic*2);
                const uint32_t mlo = __builtin_amdgcn_readfirstlane((uint32_t)raw);
                const uint32_t mhi = __builtin_amdgcn_readfirstlane((uint32_t)(raw >> 32));
                uint64_t m = ((uint64_t)mhi << 32) | mlo;
                double a0 = 0.0, a1 = 0.0, a2 = 0.0, a3 = 0.0;
                while (m) {
                    float f0 = 0.f, f1 = 0.f, f2 = 0.f, f3 = 0.f;
                    int p = __builtin_ctzll(m); m &= m - 1;
                    f0 = wsh[p*RPAD + lane];
                    if (m) { p = __builtin_ctzll(m); m &= m - 1; f1 = wsh[p*RPAD + lane]; }
                    if (m) { p = __builtin_ctzll(m); m &= m - 1; f2 = wsh[p*RPAD + lane]; }
                    if (m) { p = __builtin_ctzll(m); m &= m - 1; f3 = wsh[p*RPAD + lane]; }
                    a0 += (double)f0; a1 += (double)f1; a2 += (double)f2; a3 += (double)f3;
                }
                acc[j] += (a0 + a1) + (a2 + a3);
            }
        }
        #pragma unroll
        for (int j = 0; j < CHUNK/4; ++j) {
            const int t = t0 + wvu*(CHUNK/4) + j;
            ring[t % RING][lane] = acc[j];
        }
    };

    auto conv_chunk = [&](int c) {
        const int t0 = c * CHUNK;
        const int tl = tid & (CHUNK-1);
        const int os = tid >> 4;
        const int t  = t0 + tl;
        double u0 = 0, u1 = 0, u2 = 0, u3 = 0;
        for (int k = 1; k < KLEN; ++k) {
            const double sv  = srm64[k];
            const int    row = (t - k + RING) % RING;
            const double* ap = &ring[row][os*4];
            u0 = fma(sv, ap[0], u0);
            u1 = fma(sv, ap[1], u1);
            u2 = fma(sv, ap[2], u2);
            u3 = fma(sv, ap[3], u3);
        }
        double* upp = &ush[tl*RPAD + os*4];
        upp[0] = u0; upp[1] = u1; upp[2] = u2; upp[3] = u3;
    };

    uint64_t mask = 0;
    auto scan_chunk = [&](int c) {
        const int t0 = c * CHUNK;
        for (int tl = 0; tl < CHUNK; ++tl) {
            const double uv = ush[tl*RPAD + lane];
            uint64_t m = mask;
            double r0 = 0.0, r1 = 0.0;
            while (m) {
                int p = __builtin_ctzll(m); m &= m - 1;
                r0 += ref64[p + 1];
                if (m) { int q = __builtin_ctzll(m); m &= m - 1; r1 += ref64[q + 1]; }
            }
            const bool s = (uv + (r0 + r1)) >= THETA;
            const uint64_t bal = __ballot(s);
            if (lane == 0)
                *(uint64_t*)(bits_out + ((size_t)b*TT + (t0 + tl))*(O/32) + (o0 >> 5)) = bal;
            mask = ((mask << 1) | (s ? 1ull : 0ull)) & ((1ull << 61) - 1ull);
        }
    };

    gemm_chunk(0);
    for (int c = 0; c < NCHUNK; ++c) {
        __syncthreads();
        conv_chunk(c);
        __syncthreads();
        if (wvu == 0) scan_chunk(c);
        __syncthreads();
        if (c + 1 < NCHUNK) gemm_chunk(c + 1);
    }
}

// ================================ epilogue ==================================
__global__ __launch_bounds__(256)
void bits_to_f32(const uint32_t* __restrict__ bits, float* __restrict__ out, int O)
{
    const int b  = blockIdx.y;
    const int o  = blockIdx.x*4 + (threadIdx.x >> 6);
    const int tq = (threadIdx.x & 63) * 4;
    const uint32_t* bp  = bits + (size_t)b*TT*(O/32) + (o >> 5);
    const uint32_t  bit = 1u << (o & 31);
    float4 v;
    v.x = (bp[(size_t)(tq+0)*(O/32)] & bit) ? 1.0f : 0.0f;
    v.y = (bp[(size_t)(tq+1)*(O/32)] & bit) ? 1.0f : 0.0f;
    v.z = (bp[(size_t)(tq+2)*(O/32)] & bit) ? 1.0f : 0.0f;
    v.w = (bp[(size_t)(tq+3)*(O/32)] & bit) ? 1.0f : 0.0f;
    *(float4*)(out + ((size_t)b*O + o)*TT + tq) = v;
}

// ================================ launcher ==================================
extern "C" void kernel_launch(void* const* d_in, const int* in_sizes, int n_in,
                              void* d_out, int out_size, void* d_ws, size_t ws_size,
                              hipStream_t stream)
{
    const float* x  = (const float*)d_in[0];   // [32][1024][256]
    const float* w1 = (const float*)d_in[1];   // [2048][1024]
    const float* w2 = (const float*)d_in[2];   // [512][2048]
    float* out = (float*)d_out;                // [32][512][256]

    uint32_t* bits1 = (uint32_t*)d_ws;                       // 1 MB
    uint32_t* bitsH = bits1 + (size_t)32*256*32;             // 2 MB
    uint32_t* bits2 = bitsH + (size_t)32*256*64;             // 0.5 MB
    const size_t bitsBytes = (size_t)32*256*(32+64+16)*4;
    const size_t base = (bitsBytes + 255) & ~(size_t)255;

    // fast-path o-slice capacity: a+u need 2 * 32*256*8 = 131072 B per output
    size_t avail = (ws_size > base) ? ws_size - base : 0;
    long long osCap = (long long)(avail / 131072);
    osCap = (osCap / 256) * 256;
    if (osCap > 2048) osCap = 2048;

    bitify<<<dim3(32, 8), 256, 0, stream>>>(x, bits1);

    if (osCap >= 256) {
        double* aBuf = (double*)((char*)d_ws + base);
        double* uBuf = (double*)((char*)d_ws + base + (size_t)osCap * 65536);
        // ---- layer 1: 1024 -> 2048 ----
        for (int ob = 0; ob < 2048; ob += (int)osCap) {
            const int os = (2048 - ob < osCap) ? (2048 - ob) : (int)osCap;
            gemm_sparse<1024><<<dim3(os/64, 2, 32), 256, 0, stream>>>(
                bits1, w1 + (size_t)ob * 1024, aBuf, os);
            psp_conv<<<dim3(os/64, 4, 32), 256, 0, stream>>>(aBuf, uBuf, os);
            scan_spikes<<<dim3(os/256, 32), 256, 0, stream>>>(uBuf, bitsH, os, ob, 64);
        }
        // ---- layer 2: 2048 -> 512 ----
        for (int ob = 0; ob < 512; ob += (int)osCap) {
            const int os = (512 - ob < osCap) ? (512 - ob) : (int)osCap;
            gemm_sparse<2048><<<dim3(os/64, 2, 32), 256, 0, stream>>>(
                bitsH, w2 + (size_t)ob * 2048, aBuf, os);
            psp_conv<<<dim3(os/64, 4, 32), 256, 0, stream>>>(aBuf, uBuf, os);
            scan_spikes<<<dim3(os/256, 32), 256, 0, stream>>>(uBuf, bits2, os, ob, 16);
        }
    } else {
        // fallback: round-2 fused kernels (ws too small for f64 a/u buffers)
        snn_layer_sparse<1024><<<dim3(2048/64, 32), 256, 0, stream>>>(bits1, w1, bitsH, 2048);
        snn_layer_sparse<2048><<<dim3(512/64, 32), 256, 0, stream>>>(bitsH, w2, bits2, 512);
    }

    bits_to_f32<<<dim3(512/4, 32), 256, 0, stream>>>(bits2, out, 512);
}

// Round 4
// 1802.574 us; speedup vs baseline: 1.8258x; 1.0887x over previous
//
#include <hip/hip_runtime.h>
#include <math.h>
#include <stdint.h>

// SLAYER 2-layer SNN. Round 4: de-fused pipeline, spill fix.
//   bitify -> per layer: [sparse bit-GEMM -> dense FIR conv -> sequential scan]
//   -> bits_to_f32.
// R3 bug: __launch_bounds__(256,4) capped the gemm at 64 arch-VGPRs -> acc[32]
// spilled to scratch (598 MB writes/dispatch, 800 us). Fix: default bounds.
// All fp64 accumulation, fp32-rounded taps (absmax 0.0 in rounds 1-3).

#define TT     256
#define KLEN   62          // taps 0..61
#define THETA  10.0

// ================================ bitify ====================================
__global__ __launch_bounds__(256)
void bitify(const float* __restrict__ x, uint32_t* __restrict__ bits)
{
    const int b  = blockIdx.x;
    const int ig = blockIdx.y;            // group of 128 inputs (4 words)
    const int t  = threadIdx.x;
    const float*  xp = x    + ((size_t)b*1024 + ig*128)*TT + t;
    uint32_t*     bp = bits + ((size_t)b*TT + t)*32 + ig*4;
    for (int wi = 0; wi < 4; ++wi) {
        uint32_t wb = 0;
        #pragma unroll
        for (int j = 0; j < 32; ++j)
            wb |= (xp[(size_t)(wi*32 + j)*TT] >= 0.5f) ? (1u << j) : 0u;
        bp[wi] = wb;
    }
}

// ========================== sparse GEMM =====================================
// a[b][t][o] = sum over spiking i of w[o][i]   (fp64)
// block: 64 outputs x 128 t (4 waves x 32 t). lane = o, spike masks wave-uniform.
// NOTE: no min-waves in launch_bounds -- acc[32] (64 VGPRs) must stay in regs.
template<int I>
__global__ __launch_bounds__(256)
void gemm_sparse(const uint32_t* __restrict__ bits_in,   // [B][TT][I/32]
                 const float*    __restrict__ w,         // slice base, stride I
                 double*         __restrict__ a_out,     // [B][TT][OS]
                 int OS)
{
    constexpr int IW = I / 32;
    __shared__ float wsh[64 * 65];

    const int tid  = threadIdx.x;
    const int lane = tid & 63;
    const int wvu  = tid >> 6;
    const int b    = blockIdx.z;
    const int o0   = blockIdx.x * 64;
    const int t0   = blockIdx.y * 128 + wvu * 32;

    double acc[32];
    #pragma unroll
    for (int j = 0; j < 32; ++j) acc[j] = 0.0;

    for (int ic = 0; ic < I / 64; ++ic) {
        __syncthreads();
        {   // stage w[o0..+64][ic*64..+64] -> wsh[il][o], padded stride 65
            const int obase = tid >> 4, il4 = (tid & 15) * 4;
            #pragma unroll
            for (int p4 = 0; p4 < 4; ++p4) {
                const int oo = obase + p4 * 16;
                const float4 wv4 = *(const float4*)(w + (size_t)(o0 + oo) * I + ic * 64 + il4);
                wsh[(il4 + 0) * 65 + oo] = wv4.x;
                wsh[(il4 + 1) * 65 + oo] = wv4.y;
                wsh[(il4 + 2) * 65 + oo] = wv4.z;
                wsh[(il4 + 3) * 65 + oo] = wv4.w;
            }
        }
        __syncthreads();
        #pragma unroll
        for (int j = 0; j < 32; ++j) {
            const uint64_t raw =
                *(const uint64_t*)(bits_in + ((size_t)b * TT + t0 + j) * IW + ic * 2);
            const uint32_t mlo = __builtin_amdgcn_readfirstlane((uint32_t)raw);
            const uint32_t mhi = __builtin_amdgcn_readfirstlane((uint32_t)(raw >> 32));
            uint64_t m = ((uint64_t)mhi << 32) | mlo;
            double a0 = 0.0, a1 = 0.0, a2 = 0.0, a3 = 0.0;
            while (m) {   // 4-wide: several LDS reads in flight
                float f0 = 0.f, f1 = 0.f, f2 = 0.f, f3 = 0.f;
                int p = __builtin_ctzll(m); m &= m - 1;
                f0 = wsh[p * 65 + lane];
                if (m) { p = __builtin_ctzll(m); m &= m - 1; f1 = wsh[p * 65 + lane]; }
                if (m) { p = __builtin_ctzll(m); m &= m - 1; f2 = wsh[p * 65 + lane]; }
                if (m) { p = __builtin_ctzll(m); m &= m - 1; f3 = wsh[p * 65 + lane]; }
                a0 += (double)f0; a1 += (double)f1; a2 += (double)f2; a3 += (double)f3;
            }
            acc[j] += (a0 + a1) + (a2 + a3);
        }
    }
    double* aout = a_out + ((size_t)b * TT + t0) * OS + o0 + lane;
    #pragma unroll
    for (int j = 0; j < 32; ++j) aout[(size_t)j * OS] = acc[j];
}

// ========================== FIR conv ========================================
// u[b][t][o] = sum_{k=1..61} srm[k] * a[b][t-k][o].
// block: 64 o x 64 t tile; a staged (125 rows x 64 o) in LDS; each thread
// computes 16 t register-blocked by 4 (sliding coeff window).
__global__ __launch_bounds__(256)
void psp_conv(const double* __restrict__ a, double* __restrict__ u, int OS)
{
    __shared__ double ash[125 * 64];   // 62.5 KB
    __shared__ double srmE[68];        // srmE[i] = srm[i-2] for i-2 in [1,61], else 0

    const int tid = threadIdx.x;
    if (tid < 68) {
        const int k = tid - 2;
        double v = 0.0;
        if (k >= 1 && k <= 61) {
            double wv = (double)k / 8.0 * exp(1.0 - (double)k / 8.0);
            v = (double)(float)wv;     // fp32-rounded tap, widened
        }
        srmE[tid] = v;
    }
    const int b  = blockIdx.z;
    const int T0 = blockIdx.y * 64;
    const int og = blockIdx.x * 64;
    const double* ap = a + (size_t)b * TT * OS + og;
    for (int e = tid; e < 125 * 64; e += 256) {
        const int r = e >> 6, o = e & 63;
        const int t = T0 - 61 + r;
        ash[e] = (t >= 0) ? ap[(size_t)t * OS + o] : 0.0;
    }
    __syncthreads();

    const int o   = tid & 63;
    const int tb0 = (tid >> 6) * 16;
    for (int g = 0; g < 4; ++g) {
        const int tb = tb0 + g * 4;     // u for t = T0+tb .. +3
        double u0 = 0, u1 = 0, u2 = 0, u3 = 0;
        double w1 = srmE[64], w2 = srmE[65], w3 = srmE[66];   // zero pads
        for (int d = 0; d < 64; d += 4) {
            const double av0 = ash[(tb + d + 0) * 64 + o];
            const double av1 = ash[(tb + d + 1) * 64 + o];
            const double av2 = ash[(tb + d + 2) * 64 + o];
            const double av3 = ash[(tb + d + 3) * 64 + o];
            const double n0 = srmE[63 - d], n1 = srmE[62 - d];
            const double n2 = srmE[61 - d], n3 = srmE[60 - d];
            u0 = fma(n0, av0, u0); u1 = fma(w1, av0, u1); u2 = fma(w2, av0, u2); u3 = fma(w3, av0, u3);
            u0 = fma(n1, av1, u0); u1 = fma(n0, av1, u1); u2 = fma(w1, av1, u2); u3 = fma(w2, av1, u3);
            u0 = fma(n2, av2, u0); u1 = fma(n1, av2, u1); u2 = fma(n0, av2, u2); u3 = fma(w1, av2, u3);
            u0 = fma(n3, av3, u0); u1 = fma(n2, av3, u1); u2 = fma(n1, av3, u2); u3 = fma(n0, av3, u3);
            w1 = n3; w2 = n2; w3 = n1;
        }
        double* uo = u + ((size_t)b * TT + T0 + tb) * OS + og + o;
        uo[0] = u0; uo[OS] = u1; uo[2 * (size_t)OS] = u2; uo[3 * (size_t)OS] = u3;
    }
}

// ========================== scan ============================================
__global__ __launch_bounds__(256)
void scan_spikes(const double* __restrict__ u, uint32_t* __restrict__ bits_out,
                 int OS, int obase, int OW)
{
    __shared__ double ref64[KLEN];
    const int tid = threadIdx.x;
    if (tid < KLEN) {
        double v = (double)tid / 8.0 * exp(1.0 - (double)tid / 8.0);
        ref64[tid] = (double)(float)(-20.0 * v);
    }
    __syncthreads();

    const int b    = blockIdx.y;
    const int o    = blockIdx.x * 256 + tid;
    const int lane = tid & 63;
    const int widx = (obase + blockIdx.x * 256 + (tid >> 6) * 64) >> 5;
    const double* up = u + (size_t)b * TT * OS + o;

    uint64_t mask = 0;
    double cur0 = up[0], cur1 = up[OS], cur2 = up[2 * (size_t)OS], cur3 = up[3 * (size_t)OS];
    for (int t0 = 0; t0 < TT; t0 += 4) {
        double nx0 = 0, nx1 = 0, nx2 = 0, nx3 = 0;
        if (t0 + 4 < TT) {
            const double* pp = up + (size_t)(t0 + 4) * OS;
            nx0 = pp[0]; nx1 = pp[OS]; nx2 = pp[2 * (size_t)OS]; nx3 = pp[3 * (size_t)OS];
        }
        #pragma unroll
        for (int q = 0; q < 4; ++q) {
            const double uv = (q == 0) ? cur0 : (q == 1) ? cur1 : (q == 2) ? cur2 : cur3;
            uint64_t m = mask;
            double r0 = 0.0, r1 = 0.0;
            while (m) {
                int p = __builtin_ctzll(m); m &= m - 1;
                r0 += ref64[p + 1];
                if (m) { int pq = __builtin_ctzll(m); m &= m - 1; r1 += ref64[pq + 1]; }
            }
            const bool s = (uv + (r0 + r1)) >= THETA;
            const uint64_t bal = __ballot(s);
            if (lane == 0)
                *(uint64_t*)(bits_out + ((size_t)b * TT + t0 + q) * OW + widx) = bal;
            mask = ((mask << 1) | (s ? 1ull : 0ull)) & ((1ull << 61) - 1ull);
        }
        cur0 = nx0; cur1 = nx1; cur2 = nx2; cur3 = nx3;
    }
}

// =================== fallback: round-2 fused layer kernel ===================
#define CHUNK  16
#define NCHUNK (TT/CHUNK)
#define RING   80
#define RPAD   65

template<int I>
__global__ __launch_bounds__(256)
void snn_layer_sparse(const uint32_t* __restrict__ bits_in,
                      const float*    __restrict__ w,
                      uint32_t*       __restrict__ bits_out,
                      int O)
{
    __shared__ double ring[RING][RPAD];
    __shared__ double wu[2080];
    __shared__ double srm64[KLEN];
    __shared__ double ref64[KLEN];

    float*  wsh = (float*)wu;
    double* ush = wu;

    const int tid  = threadIdx.x;
    const int lane = tid & 63;
    const int wvu  = __builtin_amdgcn_readfirstlane(tid >> 6);
    const int b    = blockIdx.y;
    const int o0   = blockIdx.x * 64;
    const int IW   = I / 32;

    if (tid < KLEN) {
        double v = (double)tid / 8.0 * exp(1.0 - (double)tid / 8.0);
        srm64[tid] = (double)(float)v;
        ref64[tid] = (double)(float)(-20.0 * v);
    }
    for (int e = tid; e < RING*RPAD; e += 256) ((double*)ring)[e] = 0.0;

    auto gemm_chunk = [&](int c) {
        const int t0 = c * CHUNK;
        double acc[CHUNK/4];
        #pragma unroll
        for (int j = 0; j < CHUNK/4; ++j) acc[j] = 0.0;
        for (int ic = 0; ic < I/64; ++ic) {
            __syncthreads();
            {
                const int obase = tid >> 4;
                const int il4   = (tid & 15) * 4;
                #pragma unroll
                for (int p4 = 0; p4 < 4; ++p4) {
                    const int oo = obase + p4*16;
                    const float4 wv4 = *(const float4*)(w + (size_t)(o0+oo)*I + ic*64 + il4);
                    wsh[(il4+0)*RPAD + oo] = wv4.x;
                    wsh[(il4+1)*RPAD + oo] = wv4.y;
                    wsh[(il4+2)*RPAD + oo] = wv4.z;
                    wsh[(il4+3)*RPAD + oo] = wv4.w;
                }
            }
            __syncthreads();
            #pragma unroll
            for (int j = 0; j < CHUNK/4; ++j) {
                const int t = t0 + wvu*(CHUNK/4) + j;
                const uint64_t raw =
                    *(const uint64_t*)(bits_in + ((size_t)b*TT + t)*IW + ic*2);
                const uint32_t mlo = __builtin_amdgcn_readfirstlane((uint32_t)raw);
                const uint32_t mhi = __builtin_amdgcn_readfirstlane((uint32_t)(raw >> 32));
                uint64_t m = ((uint64_t)mhi << 32) | mlo;
                double a0 = 0.0, a1 = 0.0, a2 = 0.0, a3 = 0.0;
                while (m) {
                    float f0 = 0.f, f1 = 0.f, f2 = 0.f, f3 = 0.f;
                    int p = __builtin_ctzll(m); m &= m - 1;
                    f0 = wsh[p*RPAD + lane];
                    if (m) { p = __builtin_ctzll(m); m &= m - 1; f1 = wsh[p*RPAD + lane]; }
                    if (m) { p = __builtin_ctzll(m); m &= m - 1; f2 = wsh[p*RPAD + lane]; }
                    if (m) { p = __builtin_ctzll(m); m &= m - 1; f3 = wsh[p*RPAD + lane]; }
                    a0 += (double)f0; a1 += (double)f1; a2 += (double)f2; a3 += (double)f3;
                }
                acc[j] += (a0 + a1) + (a2 + a3);
            }
        }
        #pragma unroll
        for (int j = 0; j < CHUNK/4; ++j) {
            const int t = t0 + wvu*(CHUNK/4) + j;
            ring[t % RING][lane] = acc[j];
        }
    };

    auto conv_chunk = [&](int c) {
        const int t0 = c * CHUNK;
        const int tl = tid & (CHUNK-1);
        const int os = tid >> 4;
        const int t  = t0 + tl;
        double u0 = 0, u1 = 0, u2 = 0, u3 = 0;
        for (int k = 1; k < KLEN; ++k) {
            const double sv  = srm64[k];
            const int    row = (t - k + RING) % RING;
            const double* ap = &ring[row][os*4];
            u0 = fma(sv, ap[0], u0);
            u1 = fma(sv, ap[1], u1);
            u2 = fma(sv, ap[2], u2);
            u3 = fma(sv, ap[3], u3);
        }
        double* upp = &ush[tl*RPAD + os*4];
        upp[0] = u0; upp[1] = u1; upp[2] = u2; upp[3] = u3;
    };

    uint64_t mask = 0;
    auto scan_chunk = [&](int c) {
        const int t0 = c * CHUNK;
        for (int tl = 0; tl < CHUNK; ++tl) {
            const double uv = ush[tl*RPAD + lane];
            uint64_t m = mask;
            double r0 = 0.0, r1 = 0.0;
            while (m) {
                int p = __builtin_ctzll(m); m &= m - 1;
                r0 += ref64[p + 1];
                if (m) { int q = __builtin_ctzll(m); m &= m - 1; r1 += ref64[q + 1]; }
            }
            const bool s = (uv + (r0 + r1)) >= THETA;
            const uint64_t bal = __ballot(s);
            if (lane == 0)
                *(uint64_t*)(bits_out + ((size_t)b*TT + (t0 + tl))*(O/32) + (o0 >> 5)) = bal;
            mask = ((mask << 1) | (s ? 1ull : 0ull)) & ((1ull << 61) - 1ull);
        }
    };

    gemm_chunk(0);
    for (int c = 0; c < NCHUNK; ++c) {
        __syncthreads();
        conv_chunk(c);
        __syncthreads();
        if (wvu == 0) scan_chunk(c);
        __syncthreads();
        if (c + 1 < NCHUNK) gemm_chunk(c + 1);
    }
}

// ================================ epilogue ==================================
__global__ __launch_bounds__(256)
void bits_to_f32(const uint32_t* __restrict__ bits, float* __restrict__ out, int O)
{
    const int b  = blockIdx.y;
    const int o  = blockIdx.x*4 + (threadIdx.x >> 6);
    const int tq = (threadIdx.x & 63) * 4;
    const uint32_t* bp  = bits + (size_t)b*TT*(O/32) + (o >> 5);
    const uint32_t  bit = 1u << (o & 31);
    float4 v;
    v.x = (bp[(size_t)(tq+0)*(O/32)] & bit) ? 1.0f : 0.0f;
    v.y = (bp[(size_t)(tq+1)*(O/32)] & bit) ? 1.0f : 0.0f;
    v.z = (bp[(size_t)(tq+2)*(O/32)] & bit) ? 1.0f : 0.0f;
    v.w = (bp[(size_t)(tq+3)*(O/32)] & bit) ? 1.0f : 0.0f;
    *(float4*)(out + ((size_t)b*O + o)*TT + tq) = v;
}

// ================================ launcher ==================================
extern "C" void kernel_launch(void* const* d_in, const int* in_sizes, int n_in,
                              void* d_out, int out_size, void* d_ws, size_t ws_size,
                              hipStream_t stream)
{
    const float* x  = (const float*)d_in[0];   // [32][1024][256]
    const float* w1 = (const float*)d_in[1];   // [2048][1024]
    const float* w2 = (const float*)d_in[2];   // [512][2048]
    float* out = (float*)d_out;                // [32][512][256]

    uint32_t* bits1 = (uint32_t*)d_ws;                       // 1 MB
    uint32_t* bitsH = bits1 + (size_t)32*256*32;             // 2 MB
    uint32_t* bits2 = bitsH + (size_t)32*256*64;             // 0.5 MB
    const size_t bitsBytes = (size_t)32*256*(32+64+16)*4;
    const size_t base = (bitsBytes + 255) & ~(size_t)255;

    // fast-path o-slice capacity: a+u need 2 * 32*256*8 = 131072 B per output;
    // snap to a balanced power-of-two slice so layer-1 slices are equal.
    size_t avail = (ws_size > base) ? ws_size - base : 0;
    long long osCap = (long long)(avail / 131072);
    int osSlice = 0;
    if      (osCap >= 2048) osSlice = 2048;
    else if (osCap >= 1024) osSlice = 1024;
    else if (osCap >=  512) osSlice =  512;
    else if (osCap >=  256) osSlice =  256;

    bitify<<<dim3(32, 8), 256, 0, stream>>>(x, bits1);

    if (osSlice >= 256) {
        double* aBuf = (double*)((char*)d_ws + base);
        double* uBuf = (double*)((char*)d_ws + base + (size_t)osSlice * 65536);
        // ---- layer 1: 1024 -> 2048 ----
        for (int ob = 0; ob < 2048; ob += osSlice) {
            const int os = (2048 - ob < osSlice) ? (2048 - ob) : osSlice;
            gemm_sparse<1024><<<dim3(os/64, 2, 32), 256, 0, stream>>>(
                bits1, w1 + (size_t)ob * 1024, aBuf, os);
            psp_conv<<<dim3(os/64, 4, 32), 256, 0, stream>>>(aBuf, uBuf, os);
            scan_spikes<<<dim3(os/256, 32), 256, 0, stream>>>(uBuf, bitsH, os, ob, 64);
        }
        // ---- layer 2: 2048 -> 512 ----
        for (int ob = 0; ob < 512; ob += osSlice) {
            const int os = (512 - ob < osSlice) ? (512 - ob) : osSlice;
            gemm_sparse<2048><<<dim3(os/64, 2, 32), 256, 0, stream>>>(
                bitsH, w2 + (size_t)ob * 2048, aBuf, os);
            psp_conv<<<dim3(os/64, 4, 32), 256, 0, stream>>>(aBuf, uBuf, os);
            scan_spikes<<<dim3(os/256, 32), 256, 0, stream>>>(uBuf, bits2, os, ob, 16);
        }
    } else {
        snn_layer_sparse<1024><<<dim3(2048/64, 32), 256, 0, stream>>>(bits1, w1, bitsH, 2048);
        snn_layer_sparse<2048><<<dim3(512/64, 32), 256, 0, stream>>>(bitsH, w2, bits2, 512);
    }

    bits_to_f32<<<dim3(512/4, 32), 256, 0, stream>>>(bits2, out, 512);
}

// Round 5
// 1503.464 us; speedup vs baseline: 2.1891x; 1.1989x over previous
//
#include <hip/hip_runtime.h>
#include <math.h>
#include <stdint.h>

// SLAYER 2-layer SNN. Round 5: kill spike-word load latency in the sparse GEMM.
//   bitifyT -> per layer: [sparse bit-GEMM -> dense FIR conv -> sequential scan]
//   -> bits_to_f32T.
// R4 diagnosis: gemm latency-bound (VALUBusy 25%) on per-j wave-uniform global
// loads of spike words + 2 barriers/chunk. R5: transposed bit layout gives one
// coalesced load per chunk, per-j masks via v_readlane (register); w-staging is
// double-buffered (1 barrier/chunk, loads overlap compute).
// All fp64 accumulation, fp32-rounded taps, identical event order (absmax 0.0
// in rounds 1-4).

#define TT     256
#define KLEN   62          // taps 0..61
#define THETA  10.0

// ============================ bitify (transposed) ===========================
// x: [32][1024][256] f32 {0,1}; bitsT: [b][32 words][256 t]
__global__ __launch_bounds__(256)
void bitifyT(const float* __restrict__ x, uint32_t* __restrict__ bitsT)
{
    const int b  = blockIdx.x;
    const int ig = blockIdx.y;            // group of 128 inputs (4 words)
    const int t  = threadIdx.x;
    const float* xp = x     + ((size_t)b*1024 + ig*128)*TT + t;
    uint32_t*    bp = bitsT + ((size_t)b*32 + ig*4)*TT + t;
    for (int wi = 0; wi < 4; ++wi) {
        uint32_t wb = 0;
        #pragma unroll
        for (int j = 0; j < 32; ++j)
            wb |= (xp[(size_t)(wi*32 + j)*TT] >= 0.5f) ? (1u << j) : 0u;
        bp[(size_t)wi * TT] = wb;
    }
}

// ========================== sparse GEMM =====================================
// a[b][t][o] = sum over spiking i of w[o][i]   (fp64)
// block: 64 outputs x 128 t (4 waves x 32 t). lane = o.
// Spike words: one coalesced dword load per 64-i chunk (lane l holds word
// (l>>5) for t0+(l&31)); per-j masks extracted with v_readlane -> SGPRs.
template<int I>
__global__ __launch_bounds__(256)
void gemm_sparse(const uint32_t* __restrict__ bitsT,   // [B][I/32][TT]
                 const float*    __restrict__ w,       // slice base, stride I
                 double*         __restrict__ a_out,   // [B][TT][OS]
                 int OS)
{
    constexpr int IW = I / 32;
    constexpr int NC = I / 64;
    __shared__ float wsh[2][64 * 65];     // 33.3 KB double-buffered w tile

    const int tid  = threadIdx.x;
    const int lane = tid & 63;
    const int wvu  = tid >> 6;
    const int b    = blockIdx.z;
    const int o0   = blockIdx.x * 64;
    const int t0   = blockIdx.y * 128 + wvu * 32;

    double acc[32];
    #pragma unroll
    for (int j = 0; j < 32; ++j) acc[j] = 0.0;

    const int orow = tid >> 4;            // 0..15
    const int il4  = (tid & 15) * 4;

    auto ldw = [&](int ic, float4* r) {
        #pragma unroll
        for (int p4 = 0; p4 < 4; ++p4)
            r[p4] = *(const float4*)(w + (size_t)(o0 + orow + p4*16) * I + ic*64 + il4);
    };
    auto stw = [&](int buf, const float4* r) {
        #pragma unroll
        for (int p4 = 0; p4 < 4; ++p4) {
            const int oo = orow + p4 * 16;
            wsh[buf][(il4 + 0) * 65 + oo] = r[p4].x;
            wsh[buf][(il4 + 1) * 65 + oo] = r[p4].y;
            wsh[buf][(il4 + 2) * 65 + oo] = r[p4].z;
            wsh[buf][(il4 + 3) * 65 + oo] = r[p4].w;
        }
    };
    auto ldm = [&](int ic) -> uint32_t {  // coalesced: lane l -> word 2ic+(l>>5), t0+(l&31)
        return bitsT[((size_t)b * IW + 2*ic + (lane >> 5)) * TT + t0 + (lane & 31)];
    };

    float4 wreg[4];
    ldw(0, wreg);
    uint32_t mw = ldm(0);
    stw(0, wreg);
    __syncthreads();

    for (int ic = 0; ic < NC; ++ic) {
        uint32_t mwn = 0;
        const bool more = (ic + 1 < NC);
        if (more) { ldw(ic + 1, wreg); mwn = ldm(ic + 1); }   // overlap with compute

        const float* wp = wsh[ic & 1];
        #pragma unroll
        for (int j = 0; j < 32; ++j) {
            const uint32_t mlo = (uint32_t)__builtin_amdgcn_readlane((int)mw, j);
            const uint32_t mhi = (uint32_t)__builtin_amdgcn_readlane((int)mw, 32 + j);
            uint64_t m = ((uint64_t)mhi << 32) | mlo;
            double a0 = 0.0, a1 = 0.0, a2 = 0.0, a3 = 0.0;
            while (m) {   // 4-wide: several LDS reads in flight
                float f0 = 0.f, f1 = 0.f, f2 = 0.f, f3 = 0.f;
                int p = __builtin_ctzll(m); m &= m - 1;
                f0 = wp[p * 65 + lane];
                if (m) { p = __builtin_ctzll(m); m &= m - 1; f1 = wp[p * 65 + lane]; }
                if (m) { p = __builtin_ctzll(m); m &= m - 1; f2 = wp[p * 65 + lane]; }
                if (m) { p = __builtin_ctzll(m); m &= m - 1; f3 = wp[p * 65 + lane]; }
                a0 += (double)f0; a1 += (double)f1; a2 += (double)f2; a3 += (double)f3;
            }
            acc[j] += (a0 + a1) + (a2 + a3);
        }
        if (more) { stw((ic + 1) & 1, wreg); mw = mwn; }
        __syncthreads();
    }

    double* aout = a_out + ((size_t)b * TT + t0) * OS + o0 + lane;
    #pragma unroll
    for (int j = 0; j < 32; ++j) aout[(size_t)j * OS] = acc[j];
}

// ========================== FIR conv ========================================
// u[b][t][o] = sum_{k=1..61} srm[k] * a[b][t-k][o].
__global__ __launch_bounds__(256)
void psp_conv(const double* __restrict__ a, double* __restrict__ u, int OS)
{
    __shared__ double ash[125 * 64];   // 62.5 KB
    __shared__ double srmE[68];        // srmE[i] = srm[i-2] for i-2 in [1,61], else 0

    const int tid = threadIdx.x;
    if (tid < 68) {
        const int k = tid - 2;
        double v = 0.0;
        if (k >= 1 && k <= 61) {
            double wv = (double)k / 8.0 * exp(1.0 - (double)k / 8.0);
            v = (double)(float)wv;     // fp32-rounded tap, widened
        }
        srmE[tid] = v;
    }
    const int b  = blockIdx.z;
    const int T0 = blockIdx.y * 64;
    const int og = blockIdx.x * 64;
    const double* ap = a + (size_t)b * TT * OS + og;
    for (int e = tid; e < 125 * 64; e += 256) {
        const int r = e >> 6, o = e & 63;
        const int t = T0 - 61 + r;
        ash[e] = (t >= 0) ? ap[(size_t)t * OS + o] : 0.0;
    }
    __syncthreads();

    const int o   = tid & 63;
    const int tb0 = (tid >> 6) * 16;
    for (int g = 0; g < 4; ++g) {
        const int tb = tb0 + g * 4;
        double u0 = 0, u1 = 0, u2 = 0, u3 = 0;
        double w1 = srmE[64], w2 = srmE[65], w3 = srmE[66];   // zero pads
        for (int d = 0; d < 64; d += 4) {
            const double av0 = ash[(tb + d + 0) * 64 + o];
            const double av1 = ash[(tb + d + 1) * 64 + o];
            const double av2 = ash[(tb + d + 2) * 64 + o];
            const double av3 = ash[(tb + d + 3) * 64 + o];
            const double n0 = srmE[63 - d], n1 = srmE[62 - d];
            const double n2 = srmE[61 - d], n3 = srmE[60 - d];
            u0 = fma(n0, av0, u0); u1 = fma(w1, av0, u1); u2 = fma(w2, av0, u2); u3 = fma(w3, av0, u3);
            u0 = fma(n1, av1, u0); u1 = fma(n0, av1, u1); u2 = fma(w1, av1, u2); u3 = fma(w2, av1, u3);
            u0 = fma(n2, av2, u0); u1 = fma(n1, av2, u1); u2 = fma(n0, av2, u2); u3 = fma(w1, av2, u3);
            u0 = fma(n3, av3, u0); u1 = fma(n2, av3, u1); u2 = fma(n1, av3, u2); u3 = fma(n0, av3, u3);
            w1 = n3; w2 = n2; w3 = n1;
        }
        double* uo = u + ((size_t)b * TT + T0 + tb) * OS + og + o;
        uo[0] = u0; uo[OS] = u1; uo[2 * (size_t)OS] = u2; uo[3 * (size_t)OS] = u3;
    }
}

// ========================== scan (transposed output) ========================
// lane = neuron; 256 sequential steps; refractory via 61-bit history mask.
// Ballots staged in LDS then written coalesced to bitsT_out[b][word][t].
__global__ __launch_bounds__(256)
void scan_spikes(const double* __restrict__ u, uint32_t* __restrict__ bitsT_out,
                 int OS, int obase, int OW)
{
    __shared__ double   ref64[KLEN];
    __shared__ uint32_t blds[8][256];   // 8 KB ballot staging
    const int tid = threadIdx.x;
    if (tid < KLEN) {
        double v = (double)tid / 8.0 * exp(1.0 - (double)tid / 8.0);
        ref64[tid] = (double)(float)(-20.0 * v);
    }
    __syncthreads();

    const int b    = blockIdx.y;
    const int o    = blockIdx.x * 256 + tid;   // within slice
    const int lane = tid & 63;
    const int wv   = tid >> 6;
    const double* up = u + (size_t)b * TT * OS + o;

    uint64_t mask = 0;
    double cur0 = up[0], cur1 = up[OS], cur2 = up[2 * (size_t)OS], cur3 = up[3 * (size_t)OS];
    for (int t0 = 0; t0 < TT; t0 += 4) {
        double nx0 = 0, nx1 = 0, nx2 = 0, nx3 = 0;
        if (t0 + 4 < TT) {
            const double* pp = up + (size_t)(t0 + 4) * OS;
            nx0 = pp[0]; nx1 = pp[OS]; nx2 = pp[2 * (size_t)OS]; nx3 = pp[3 * (size_t)OS];
        }
        #pragma unroll
        for (int q = 0; q < 4; ++q) {
            const double uv = (q == 0) ? cur0 : (q == 1) ? cur1 : (q == 2) ? cur2 : cur3;
            uint64_t m = mask;
            double r0 = 0.0, r1 = 0.0;
            while (m) {
                int p = __builtin_ctzll(m); m &= m - 1;
                r0 += ref64[p + 1];
                if (m) { int pq = __builtin_ctzll(m); m &= m - 1; r1 += ref64[pq + 1]; }
            }
            const bool s = (uv + (r0 + r1)) >= THETA;
            const uint64_t bal = __ballot(s);
            if (lane == 0) {
                blds[wv * 2 + 0][t0 + q] = (uint32_t)bal;
                blds[wv * 2 + 1][t0 + q] = (uint32_t)(bal >> 32);
            }
            mask = ((mask << 1) | (s ? 1ull : 0ull)) & ((1ull << 61) - 1ull);
        }
        cur0 = nx0; cur1 = nx1; cur2 = nx2; cur3 = nx3;
    }
    __syncthreads();
    const int wordbase = (obase + blockIdx.x * 256) >> 5;
    for (int e = tid; e < 8 * 256; e += 256) {
        const int wl = e >> 8, t = e & 255;
        bitsT_out[((size_t)b * OW + wordbase + wl) * TT + t] = blds[wl][t];
    }
}

// ============================ epilogue (transposed) =========================
__global__ __launch_bounds__(256)
void bits_to_f32T(const uint32_t* __restrict__ bitsT, float* __restrict__ out, int OW)
{
    const int b  = blockIdx.y;
    const int o  = blockIdx.x * 4 + (threadIdx.x >> 6);
    const int tq = (threadIdx.x & 63) * 4;
    const uint32_t* bp  = bitsT + ((size_t)b * OW + (o >> 5)) * TT + tq;
    const uint32_t  bit = 1u << (o & 31);
    float4 v;
    v.x = (bp[0] & bit) ? 1.0f : 0.0f;
    v.y = (bp[1] & bit) ? 1.0f : 0.0f;
    v.z = (bp[2] & bit) ? 1.0f : 0.0f;
    v.w = (bp[3] & bit) ? 1.0f : 0.0f;
    *(float4*)(out + ((size_t)b * 512 + o) * TT + tq) = v;
}

// =================== fallback: round-2 fused path (old layouts) =============
__global__ __launch_bounds__(256)
void bitify_rowmajor(const float* __restrict__ x, uint32_t* __restrict__ bits)
{
    const int b  = blockIdx.x;
    const int ig = blockIdx.y;
    const int t  = threadIdx.x;
    const float*  xp = x    + ((size_t)b*1024 + ig*128)*TT + t;
    uint32_t*     bp = bits + ((size_t)b*TT + t)*32 + ig*4;
    for (int wi = 0; wi < 4; ++wi) {
        uint32_t wb = 0;
        #pragma unroll
        for (int j = 0; j < 32; ++j)
            wb |= (xp[(size_t)(wi*32 + j)*TT] >= 0.5f) ? (1u << j) : 0u;
        bp[wi] = wb;
    }
}

#define CHUNK  16
#define NCHUNK (TT/CHUNK)
#define RING   80
#define RPAD   65

template<int I>
__global__ __launch_bounds__(256)
void snn_layer_sparse(const uint32_t* __restrict__ bits_in,
                      const float*    __restrict__ w,
                      uint32_t*       __restrict__ bits_out,
                      int O)
{
    __shared__ double ring[RING][RPAD];
    __shared__ double wu[2080];
    __shared__ double srm64[KLEN];
    __shared__ double ref64[KLEN];

    float*  wsh = (float*)wu;
    double* ush = wu;

    const int tid  = threadIdx.x;
    const int lane = tid & 63;
    const int wvu  = __builtin_amdgcn_readfirstlane(tid >> 6);
    const int b    = blockIdx.y;
    const int o0   = blockIdx.x * 64;
    const int IW   = I / 32;

    if (tid < KLEN) {
        double v = (double)tid / 8.0 * exp(1.0 - (double)tid / 8.0);
        srm64[tid] = (double)(float)v;
        ref64[tid] = (double)(float)(-20.0 * v);
    }
    for (int e = tid; e < RING*RPAD; e += 256) ((double*)ring)[e] = 0.0;

    auto gemm_chunk = [&](int c) {
        const int t0 = c * CHUNK;
        double acc[CHUNK/4];
        #pragma unroll
        for (int j = 0; j < CHUNK/4; ++j) acc[j] = 0.0;
        for (int ic = 0; ic < I/64; ++ic) {
            __syncthreads();
            {
                const int obase = tid >> 4;
                const int il4   = (tid & 15) * 4;
                #pragma unroll
                for (int p4 = 0; p4 < 4; ++p4) {
                    const int oo = obase + p4*16;
                    const float4 wv4 = *(const float4*)(w + (size_t)(o0+oo)*I + ic*64 + il4);
                    wsh[(il4+0)*RPAD + oo] = wv4.x;
                    wsh[(il4+1)*RPAD + oo] = wv4.y;
                    wsh[(il4+2)*RPAD + oo] = wv4.z;
                    wsh[(il4+3)*RPAD + oo] = wv4.w;
                }
            }
            __syncthreads();
            #pragma unroll
            for (int j = 0; j < CHUNK/4; ++j) {
                const int t = t0 + wvu*(CHUNK/4) + j;
                const uint64_t raw =
                    *(const uint64_t*)(bits_in + ((size_t)b*TT + t)*IW + ic*2);
                const uint32_t mlo = __builtin_amdgcn_readfirstlane((uint32_t)raw);
                const uint32_t mhi = __builtin_amdgcn_readfirstlane((uint32_t)(raw >> 32));
                uint64_t m = ((uint64_t)mhi << 32) | mlo;
                double a0 = 0.0, a1 = 0.0, a2 = 0.0, a3 = 0.0;
                while (m) {
                    float f0 = 0.f, f1 = 0.f, f2 = 0.f, f3 = 0.f;
                    int p = __builtin_ctzll(m); m &= m - 1;
                    f0 = wsh[p*RPAD + lane];
                    if (m) { p = __builtin_ctzll(m); m &= m - 1; f1 = wsh[p*RPAD + lane]; }
                    if (m) { p = __builtin_ctzll(m); m &= m - 1; f2 = wsh[p*RPAD + lane]; }
                    if (m) { p = __builtin_ctzll(m); m &= m - 1; f3 = wsh[p*RPAD + lane]; }
                    a0 += (double)f0; a1 += (double)f1; a2 += (double)f2; a3 += (double)f3;
                }
                acc[j] += (a0 + a1) + (a2 + a3);
            }
        }
        #pragma unroll
        for (int j = 0; j < CHUNK/4; ++j) {
            const int t = t0 + wvu*(CHUNK/4) + j;
            ring[t % RING][lane] = acc[j];
        }
    };

    auto conv_chunk = [&](int c) {
        const int t0 = c * CHUNK;
        const int tl = tid & (CHUNK-1);
        const int os = tid >> 4;
        const int t  = t0 + tl;
        double u0 = 0, u1 = 0, u2 = 0, u3 = 0;
        for (int k = 1; k < KLEN; ++k) {
            const double sv  = srm64[k];
            const int    row = (t - k + RING) % RING;
            const double* ap = &ring[row][os*4];
            u0 = fma(sv, ap[0], u0);
            u1 = fma(sv, ap[1], u1);
            u2 = fma(sv, ap[2], u2);
            u3 = fma(sv, ap[3], u3);
        }
        double* upp = &ush[tl*RPAD + os*4];
        upp[0] = u0; upp[1] = u1; upp[2] = u2; upp[3] = u3;
    };

    uint64_t mask = 0;
    auto scan_chunk = [&](int c) {
        const int t0 = c * CHUNK;
        for (int tl = 0; tl < CHUNK; ++tl) {
            const double uv = ush[tl*RPAD + lane];
            uint64_t m = mask;
            double r0 = 0.0, r1 = 0.0;
            while (m) {
                int p = __builtin_ctzll(m); m &= m - 1;
                r0 += ref64[p + 1];
                if (m) { int q = __builtin_ctzll(m); m &= m - 1; r1 += ref64[q + 1]; }
            }
            const bool s = (uv + (r0 + r1)) >= THETA;
            const uint64_t bal = __ballot(s);
            if (lane == 0)
                *(uint64_t*)(bits_out + ((size_t)b*TT + (t0 + tl))*(O/32) + (o0 >> 5)) = bal;
            mask = ((mask << 1) | (s ? 1ull : 0ull)) & ((1ull << 61) - 1ull);
        }
    };

    gemm_chunk(0);
    for (int c = 0; c < NCHUNK; ++c) {
        __syncthreads();
        conv_chunk(c);
        __syncthreads();
        if (wvu == 0) scan_chunk(c);
        __syncthreads();
        if (c + 1 < NCHUNK) gemm_chunk(c + 1);
    }
}

__global__ __launch_bounds__(256)
void bits_to_f32_rowmajor(const uint32_t* __restrict__ bits, float* __restrict__ out, int O)
{
    const int b  = blockIdx.y;
    const int o  = blockIdx.x*4 + (threadIdx.x >> 6);
    const int tq = (threadIdx.x & 63) * 4;
    const uint32_t* bp  = bits + (size_t)b*TT*(O/32) + (o >> 5);
    const uint32_t  bit = 1u << (o & 31);
    float4 v;
    v.x = (bp[(size_t)(tq+0)*(O/32)] & bit) ? 1.0f : 0.0f;
    v.y = (bp[(size_t)(tq+1)*(O/32)] & bit) ? 1.0f : 0.0f;
    v.z = (bp[(size_t)(tq+2)*(O/32)] & bit) ? 1.0f : 0.0f;
    v.w = (bp[(size_t)(tq+3)*(O/32)] & bit) ? 1.0f : 0.0f;
    *(float4*)(out + ((size_t)b*O + o)*TT + tq) = v;
}

// ================================ launcher ==================================
extern "C" void kernel_launch(void* const* d_in, const int* in_sizes, int n_in,
                              void* d_out, int out_size, void* d_ws, size_t ws_size,
                              hipStream_t stream)
{
    const float* x  = (const float*)d_in[0];   // [32][1024][256]
    const float* w1 = (const float*)d_in[1];   // [2048][1024]
    const float* w2 = (const float*)d_in[2];   // [512][2048]
    float* out = (float*)d_out;                // [32][512][256]

    uint32_t* bits1 = (uint32_t*)d_ws;                       // 1 MB
    uint32_t* bitsH = bits1 + (size_t)32*256*32;             // 2 MB
    uint32_t* bits2 = bitsH + (size_t)32*256*64;             // 0.5 MB
    const size_t bitsBytes = (size_t)32*256*(32+64+16)*4;
    const size_t base = (bitsBytes + 255) & ~(size_t)255;

    // a+u need 2 * 32*256*8 = 131072 B per output; balanced power-of-two slice
    size_t avail = (ws_size > base) ? ws_size - base : 0;
    long long osCap = (long long)(avail / 131072);
    int osSlice = 0;
    if      (osCap >= 2048) osSlice = 2048;
    else if (osCap >= 1024) osSlice = 1024;
    else if (osCap >=  512) osSlice =  512;
    else if (osCap >=  256) osSlice =  256;

    if (osSlice >= 256) {
        double* aBuf = (double*)((char*)d_ws + base);
        double* uBuf = (double*)((char*)d_ws + base + (size_t)osSlice * 65536);

        bitifyT<<<dim3(32, 8), 256, 0, stream>>>(x, bits1);
        // ---- layer 1: 1024 -> 2048 ----
        for (int ob = 0; ob < 2048; ob += osSlice) {
            const int os = (2048 - ob < osSlice) ? (2048 - ob) : osSlice;
            gemm_sparse<1024><<<dim3(os/64, 2, 32), 256, 0, stream>>>(
                bits1, w1 + (size_t)ob * 1024, aBuf, os);
            psp_conv<<<dim3(os/64, 4, 32), 256, 0, stream>>>(aBuf, uBuf, os);
            scan_spikes<<<dim3(os/256, 32), 256, 0, stream>>>(uBuf, bitsH, os, ob, 64);
        }
        // ---- layer 2: 2048 -> 512 ----
        for (int ob = 0; ob < 512; ob += osSlice) {
            const int os = (512 - ob < osSlice) ? (512 - ob) : osSlice;
            gemm_sparse<2048><<<dim3(os/64, 2, 32), 256, 0, stream>>>(
                bitsH, w2 + (size_t)ob * 2048, aBuf, os);
            psp_conv<<<dim3(os/64, 4, 32), 256, 0, stream>>>(aBuf, uBuf, os);
            scan_spikes<<<dim3(os/256, 32), 256, 0, stream>>>(uBuf, bits2, os, ob, 16);
        }
        bits_to_f32T<<<dim3(512/4, 32), 256, 0, stream>>>(bits2, out, 16);
    } else {
        // fallback: round-2 fused path (row-major bit layouts)
        bitify_rowmajor<<<dim3(32, 8), 256, 0, stream>>>(x, bits1);
        snn_layer_sparse<1024><<<dim3(2048/64, 32), 256, 0, stream>>>(bits1, w1, bitsH, 2048);
        snn_layer_sparse<2048><<<dim3(512/64, 32), 256, 0, stream>>>(bitsH, w2, bits2, 512);
        bits_to_f32_rowmajor<<<dim3(512/4, 32), 256, 0, stream>>>(bits2, out, 512);
    }
}